// Round 7
// baseline (235.053 us; speedup 1.0000x reference)
//
#include <hip/hip_runtime.h>

#define OUTD 7
#define SRD 2
#define PD (OUTD * SRD)   // 14 sample coords per axis
#define NCH 256
#define CHUNK 64          // channels per block -> grid (N, 4)

// ---------------- prepass: sort ROIs by (level, img, morton) ----------------
__global__ __launch_bounds__(1024)
void sort_kernel(const float* __restrict__ boxes,
                 const int*   __restrict__ img_ids,
                 int* __restrict__ order, int N)
{
    __shared__ unsigned long long kv[1024];
    const int t = threadIdx.x;

    unsigned int key = 0xFFFFFFFFu;
    if (t < N) {
        const float bx1 = boxes[t * 4 + 0];
        const float by1 = boxes[t * 4 + 1];
        const float bx2 = boxes[t * 4 + 2];
        const float by2 = boxes[t * 4 + 3];
        const float area = (bx2 - bx1) * (by2 - by1);
        const float s = sqrtf(area);
        float lvlf = floorf(4.0f + log2f(s / 224.0f + 1e-6f));
        lvlf = fminf(fmaxf(lvlf, 2.0f), 5.0f);
        const int lvl = (int)lvlf - 2;
        const float scales[4] = {0.25f, 0.125f, 0.0625f, 0.03125f};
        const float sc = scales[lvl];
        int cx = (int)(0.5f * (bx1 + bx2) * sc);
        int cy = (int)(0.5f * (by1 + by2) * sc);
        cx = min(max(cx, 0), 127);
        cy = min(max(cy, 0), 127);
        unsigned int m = 0;
#pragma unroll
        for (int b = 0; b < 7; ++b)
            m |= ((cy >> b) & 1u) << (2 * b + 1) | ((cx >> b) & 1u) << (2 * b);
        key = ((((unsigned)lvl << 1) | (unsigned)img_ids[t]) << 14) | m;
    }
    kv[t] = ((unsigned long long)key << 32) | (unsigned)t;
    __syncthreads();

    for (int k = 2; k <= 1024; k <<= 1) {
        for (int j = k >> 1; j > 0; j >>= 1) {
            const int ixj = t ^ j;
            if (ixj > t) {
                const bool up = ((t & k) == 0);
                const unsigned long long a = kv[t], b = kv[ixj];
                if ((a > b) == up) { kv[t] = b; kv[ixj] = a; }
            }
            __syncthreads();
        }
    }
    if (t < N) order[t] = (int)(kv[t] & 0xFFFFFFFFu);
}

// ---------------- main pooler ----------------
__global__ __launch_bounds__(256)
void pooler_kernel(const float* __restrict__ f0,
                   const float* __restrict__ f1,
                   const float* __restrict__ f2,
                   const float* __restrict__ f3,
                   const float* __restrict__ boxes,
                   const int*   __restrict__ img_ids,
                   const int*   __restrict__ order,
                   float* __restrict__ out, int N)
{
    int bx = blockIdx.x;
    int sidx;
    if ((N & 7) == 0) {
        sidx = (bx & 7) * (N >> 3) + (bx >> 3);   // XCD-contiguous runs
    } else {
        sidx = bx;
    }
    const int roi = order[sidx];

    const int c0  = blockIdx.y * CHUNK;
    const int t   = threadIdx.x;

    const float bx1 = boxes[roi * 4 + 0];
    const float by1 = boxes[roi * 4 + 1];
    const float bx2 = boxes[roi * 4 + 2];
    const float by2 = boxes[roi * 4 + 3];

    const float area = (bx2 - bx1) * (by2 - by1);
    const float s    = sqrtf(area);
    float lvlf = floorf(4.0f + log2f(s / 224.0f + 1e-6f));
    lvlf = fminf(fmaxf(lvlf, 2.0f), 5.0f);
    const int lvl = (int)lvlf - 2;   // 0..3

    const float scales[4] = {0.25f, 0.125f, 0.0625f, 0.03125f};
    const int   dims[4]   = {200, 100, 50, 25};
    const float* feats[4] = {f0, f1, f2, f3};

    const float scale = scales[lvl];
    const int H = dims[lvl];
    const int W = H;
    const int plane = H * W;

    const int img = img_ids[roi];
    const float* __restrict__ base0 =
        feats[lvl] + (size_t)img * NCH * (size_t)plane + (size_t)c0 * plane;

    const float x1 = bx1 * scale, y1 = by1 * scale;
    const float x2 = bx2 * scale, y2 = by2 * scale;
    const float roi_w = fmaxf(x2 - x1, 1.0f);
    const float roi_h = fmaxf(y2 - y1, 1.0f);
    const float bw = roi_w / (float)OUTD;
    const float bh = roi_h / (float)OUTD;

    __shared__ float4 s_yt[PD];
    __shared__ float4 s_xt[PD];
    __shared__ float4 s_xw[OUTD];
    __shared__ int    s_xf[OUTD];
    __shared__ int    s_ok[OUTD];

    if (t < PD) {
        const int i = t >> 1, j = t & 1;
        const float yg = y1 + (float)i * bh + ((float)j + 0.5f) * bh * 0.5f;
        const float v = ((yg >= -1.0f) && (yg <= (float)H)) ? 1.0f : 0.0f;
        const float y = fminf(fmaxf(yg, 0.0f), (float)(H - 1));
        const int y0 = (int)floorf(y);
        const int y1i = min(y0 + 1, H - 1);
        const float ly = y - (float)y0;
        float4 r;
        r.x = __int_as_float(y0 * W);
        r.y = __int_as_float(y1i * W);
        r.z = (1.0f - ly) * v;
        r.w = ly * v;
        s_yt[t] = r;
    } else if (t < 2 * PD) {
        const int tt = t - PD;
        const int i = tt >> 1, j = tt & 1;
        const float xg = x1 + (float)i * bw + ((float)j + 0.5f) * bw * 0.5f;
        const float v = ((xg >= -1.0f) && (xg <= (float)W)) ? 1.0f : 0.0f;
        const float x = fminf(fmaxf(xg, 0.0f), (float)(W - 1));
        const int x0 = (int)floorf(x);
        const float lx = x - (float)x0;
        const float hx = 1.0f - lx;
        const int edge = (x0 == W - 1);
        float4 r;
        r.x = __int_as_float(min(x0, W - 2));
        r.y = edge ? 0.0f   : hx * v;
        r.z = edge ? hx * v : lx * v;
        r.w = 0.0f;
        s_xt[tt] = r;
    } else if (t < 2 * PD + OUTD) {
        const int pw = t - 2 * PD;
        float w[4] = {0.0f, 0.0f, 0.0f, 0.0f};
        int ca[2], cb[2];
        float hxv[2], lxv[2];
#pragma unroll
        for (int j = 0; j < 2; ++j) {
            const float xg = x1 + (float)pw * bw + ((float)j + 0.5f) * bw * 0.5f;
            const float v = ((xg >= -1.0f) && (xg <= (float)W)) ? 1.0f : 0.0f;
            const float x = fminf(fmaxf(xg, 0.0f), (float)(W - 1));
            const int x0 = (int)floorf(x);
            const float lx = x - (float)x0;
            ca[j] = x0;
            cb[j] = min(x0 + 1, W - 1);
            hxv[j] = (1.0f - lx) * v;
            lxv[j] = lx * v;
        }
        const int ok = (cb[1] - ca[0]) <= 3;
        int xf = min(ca[0], W - 4);
        if (xf < 0) xf = 0;
        w[(ca[0] - xf) & 3] += hxv[0];
        w[(cb[0] - xf) & 3] += lxv[0];
        w[(ca[1] - xf) & 3] += hxv[1];
        w[(cb[1] - xf) & 3] += lxv[1];
        float4 wv; wv.x = w[0]; wv.y = w[1]; wv.z = w[2]; wv.w = w[3];
        s_xw[pw] = wv;
        s_xf[pw] = xf;
        s_ok[pw] = ok;
    }
    __syncthreads();

    const bool fused = s_ok[0] && s_ok[1] && s_ok[2] && s_ok[3] &&
                       s_ok[4] && s_ok[5] && s_ok[6];   // block-uniform

    float* __restrict__ outbase = out + ((size_t)roi * NCH + c0) * 49;

    if (fused) {
        // ======== fast path: 4 dwordx4 per element, 6-deep pipeline (24 outstanding) ========
        auto g4 = [&](const float* __restrict__ fp, int ph, int pw, float4* P) {
            const float4 yt0 = s_yt[2 * ph];
            const float4 yt1 = s_yt[2 * ph + 1];
            const int xf = s_xf[pw];
            P[0] = *(const float4*)(fp + __float_as_int(yt0.x) + xf);
            P[1] = *(const float4*)(fp + __float_as_int(yt0.y) + xf);
            P[2] = *(const float4*)(fp + __float_as_int(yt1.x) + xf);
            P[3] = *(const float4*)(fp + __float_as_int(yt1.y) + xf);
        };
        auto r4 = [&](int ph, int pw, const float4* P) -> float {
            const float4 w   = s_xw[pw];
            const float4 yt0 = s_yt[2 * ph];
            const float4 yt1 = s_yt[2 * ph + 1];
            const float d0 = w.x * P[0].x + w.y * P[0].y + w.z * P[0].z + w.w * P[0].w;
            const float d1 = w.x * P[1].x + w.y * P[1].y + w.z * P[1].z + w.w * P[1].w;
            const float d2 = w.x * P[2].x + w.y * P[2].y + w.z * P[2].z + w.w * P[2].w;
            const float d3 = w.x * P[3].x + w.y * P[3].y + w.z * P[3].z + w.w * P[3].w;
            return yt0.z * d0 + yt0.w * d1 + yt1.z * d2 + yt1.w * d3;
        };

        // 3136 = 2*1536 + 64
        int e0 = t;
#pragma unroll
        for (int kk = 0; kk < 2; ++kk) {
            int eA[6], phA[6], pwA[6];
            const float* fpA[6];
#pragma unroll
            for (int j = 0; j < 6; ++j) {
                const int e = e0 + j * 256;
                const int c = e / 49, bin = e - c * 49;
                phA[j] = bin / 7;
                pwA[j] = bin - phA[j] * 7;
                eA[j]  = e;
                fpA[j] = base0 + (size_t)c * plane;
            }
            float4 P[6][4];
#pragma unroll
            for (int j = 0; j < 6; ++j)
                g4(fpA[j], phA[j], pwA[j], P[j]);
#pragma unroll
            for (int j = 0; j < 6; ++j)
                outbase[eA[j]] = r4(phA[j], pwA[j], P[j]) * 0.25f;
            e0 += 1536;
        }
        if (t < 64) {
            const int e = 3072 + t;
            const int c = e / 49, bin = e - c * 49;
            const int ph = bin / 7, pw = bin - ph * 7;
            const float* fp = base0 + (size_t)c * plane;
            float4 P[4];
            g4(fp, ph, pw, P);
            outbase[e] = r4(ph, pw, P) * 0.25f;
        }
    } else {
        // ======== legacy path (wide bins): 8 dwordx2 per element, 3-deep (24 outstanding) ========
        auto gather = [&](const float* __restrict__ fp, int ph, int pw, float2* P) {
#pragma unroll
            for (int sy = 0; sy < SRD; ++sy) {
                const float4 yt = s_yt[ph * SRD + sy];
                const int ro0 = __float_as_int(yt.x);
                const int ro1 = __float_as_int(yt.y);
#pragma unroll
                for (int sx = 0; sx < SRD; ++sx) {
                    const float4 xt = s_xt[pw * SRD + sx];
                    const int xa = __float_as_int(xt.x);
                    P[(sy * SRD + sx) * 2 + 0] = *(const float2*)(fp + ro0 + xa);
                    P[(sy * SRD + sx) * 2 + 1] = *(const float2*)(fp + ro1 + xa);
                }
            }
        };
        auto reduce = [&](int ph, int pw, const float2* P) -> float {
            float acc = 0.0f;
#pragma unroll
            for (int sy = 0; sy < SRD; ++sy) {
                const float4 yt = s_yt[ph * SRD + sy];
                const float hy = yt.z, ly = yt.w;
#pragma unroll
                for (int sx = 0; sx < SRD; ++sx) {
                    const float4 xt = s_xt[pw * SRD + sx];
                    const float wlo = xt.y, whi = xt.z;
                    const float2 p0 = P[(sy * SRD + sx) * 2 + 0];
                    const float2 p1 = P[(sy * SRD + sx) * 2 + 1];
                    acc += hy * (wlo * p0.x + whi * p0.y)
                         + ly * (wlo * p1.x + whi * p1.y);
                }
            }
            return acc;
        };

        // 3136 = 4*768 + 64
        int e0 = t;
#pragma unroll
        for (int kk = 0; kk < 4; ++kk) {
            int eA[3], phA[3], pwA[3];
            const float* fpA[3];
#pragma unroll
            for (int j = 0; j < 3; ++j) {
                const int e = e0 + j * 256;
                const int c = e / 49, bin = e - c * 49;
                phA[j] = bin / 7;
                pwA[j] = bin - phA[j] * 7;
                eA[j]  = e;
                fpA[j] = base0 + (size_t)c * plane;
            }
            float2 P[3][8];
#pragma unroll
            for (int j = 0; j < 3; ++j)
                gather(fpA[j], phA[j], pwA[j], P[j]);
#pragma unroll
            for (int j = 0; j < 3; ++j)
                outbase[eA[j]] = reduce(phA[j], pwA[j], P[j]) * 0.25f;
            e0 += 768;
        }
        if (t < 64) {
            const int e = 3072 + t;
            const int c = e / 49, bin = e - c * 49;
            const int ph = bin / 7, pw = bin - ph * 7;
            const float* fp = base0 + (size_t)c * plane;
            float2 P[8];
            gather(fp, ph, pw, P);
            outbase[e] = reduce(ph, pw, P) * 0.25f;
        }
    }
}

extern "C" void kernel_launch(void* const* d_in, const int* in_sizes, int n_in,
                              void* d_out, int out_size, void* d_ws, size_t ws_size,
                              hipStream_t stream) {
    const float* f0    = (const float*)d_in[0];
    const float* f1    = (const float*)d_in[1];
    const float* f2    = (const float*)d_in[2];
    const float* f3    = (const float*)d_in[3];
    const float* boxes = (const float*)d_in[4];
    const int*   ids   = (const int*)d_in[5];
    float* out = (float*)d_out;
    int*   order = (int*)d_ws;

    const int N = in_sizes[4] / 4;   // number of ROIs (1000)

    sort_kernel<<<1, 1024, 0, stream>>>(boxes, ids, order, N);

    dim3 grid(N, NCH / CHUNK);
    pooler_kernel<<<grid, 256, 0, stream>>>(f0, f1, f2, f3, boxes, ids, order, out, N);
}

// Round 8
// 226.724 us; speedup vs baseline: 1.0367x; 1.0367x over previous
//
#include <hip/hip_runtime.h>

#define OUTD 7
#define SRD 2
#define PD (OUTD * SRD)   // 14 sample coords per axis
#define NCH 256
#define CHUNK 32          // channels per block -> grid (N, 8), 1568 elems/block

// ---------------- prepass: sort ROIs by (level, img, morton) ----------------
__global__ __launch_bounds__(1024)
void sort_kernel(const float* __restrict__ boxes,
                 const int*   __restrict__ img_ids,
                 int* __restrict__ order, int N)
{
    __shared__ unsigned long long kv[1024];
    const int t = threadIdx.x;

    unsigned int key = 0xFFFFFFFFu;
    if (t < N) {
        const float bx1 = boxes[t * 4 + 0];
        const float by1 = boxes[t * 4 + 1];
        const float bx2 = boxes[t * 4 + 2];
        const float by2 = boxes[t * 4 + 3];
        const float area = (bx2 - bx1) * (by2 - by1);
        const float s = sqrtf(area);
        float lvlf = floorf(4.0f + log2f(s / 224.0f + 1e-6f));
        lvlf = fminf(fmaxf(lvlf, 2.0f), 5.0f);
        const int lvl = (int)lvlf - 2;
        const float scales[4] = {0.25f, 0.125f, 0.0625f, 0.03125f};
        const float sc = scales[lvl];
        int cx = (int)(0.5f * (bx1 + bx2) * sc);
        int cy = (int)(0.5f * (by1 + by2) * sc);
        cx = min(max(cx, 0), 127);
        cy = min(max(cy, 0), 127);
        unsigned int m = 0;
#pragma unroll
        for (int b = 0; b < 7; ++b)
            m |= ((cy >> b) & 1u) << (2 * b + 1) | ((cx >> b) & 1u) << (2 * b);
        key = ((((unsigned)lvl << 1) | (unsigned)img_ids[t]) << 14) | m;
    }
    kv[t] = ((unsigned long long)key << 32) | (unsigned)t;
    __syncthreads();

    for (int k = 2; k <= 1024; k <<= 1) {
        for (int j = k >> 1; j > 0; j >>= 1) {
            const int ixj = t ^ j;
            if (ixj > t) {
                const bool up = ((t & k) == 0);
                const unsigned long long a = kv[t], b = kv[ixj];
                if ((a > b) == up) { kv[t] = b; kv[ixj] = a; }
            }
            __syncthreads();
        }
    }
    if (t < N) order[t] = (int)(kv[t] & 0xFFFFFFFFu);
}

// ---------------- main pooler ----------------
__global__ __launch_bounds__(256)
void pooler_kernel(const float* __restrict__ f0,
                   const float* __restrict__ f1,
                   const float* __restrict__ f2,
                   const float* __restrict__ f3,
                   const float* __restrict__ boxes,
                   const int*   __restrict__ img_ids,
                   const int*   __restrict__ order,
                   float* __restrict__ out, int N)
{
    int bx = blockIdx.x;
    int sidx;
    if ((N & 7) == 0) {
        sidx = (bx & 7) * (N >> 3) + (bx >> 3);   // XCD-contiguous runs
    } else {
        sidx = bx;
    }
    const int roi = order[sidx];

    const int c0  = blockIdx.y * CHUNK;
    const int t   = threadIdx.x;

    const float bx1 = boxes[roi * 4 + 0];
    const float by1 = boxes[roi * 4 + 1];
    const float bx2 = boxes[roi * 4 + 2];
    const float by2 = boxes[roi * 4 + 3];

    const float area = (bx2 - bx1) * (by2 - by1);
    const float s    = sqrtf(area);
    float lvlf = floorf(4.0f + log2f(s / 224.0f + 1e-6f));
    lvlf = fminf(fmaxf(lvlf, 2.0f), 5.0f);
    const int lvl = (int)lvlf - 2;   // 0..3

    const float scales[4] = {0.25f, 0.125f, 0.0625f, 0.03125f};
    const int   dims[4]   = {200, 100, 50, 25};
    const float* feats[4] = {f0, f1, f2, f3};

    const float scale = scales[lvl];
    const int H = dims[lvl];
    const int W = H;
    const int plane = H * W;

    const int img = img_ids[roi];
    const float* __restrict__ base0 =
        feats[lvl] + (size_t)img * NCH * (size_t)plane + (size_t)c0 * plane;

    const float x1 = bx1 * scale, y1 = by1 * scale;
    const float x2 = bx2 * scale, y2 = by2 * scale;
    const float roi_w = fmaxf(x2 - x1, 1.0f);
    const float roi_h = fmaxf(y2 - y1, 1.0f);
    const float bw = roi_w / (float)OUTD;
    const float bh = roi_h / (float)OUTD;

    __shared__ float4 s_yt[PD];
    __shared__ float4 s_xt[PD];
    __shared__ float4 s_xw[OUTD];
    __shared__ int    s_xf[OUTD];
    __shared__ int    s_ok[OUTD];

    if (t < PD) {
        const int i = t >> 1, j = t & 1;
        const float yg = y1 + (float)i * bh + ((float)j + 0.5f) * bh * 0.5f;
        const float v = ((yg >= -1.0f) && (yg <= (float)H)) ? 1.0f : 0.0f;
        const float y = fminf(fmaxf(yg, 0.0f), (float)(H - 1));
        const int y0 = (int)floorf(y);
        const int y1i = min(y0 + 1, H - 1);
        const float ly = y - (float)y0;
        float4 r;
        r.x = __int_as_float(y0 * W);
        r.y = __int_as_float(y1i * W);
        r.z = (1.0f - ly) * v;
        r.w = ly * v;
        s_yt[t] = r;
    } else if (t < 2 * PD) {
        const int tt = t - PD;
        const int i = tt >> 1, j = tt & 1;
        const float xg = x1 + (float)i * bw + ((float)j + 0.5f) * bw * 0.5f;
        const float v = ((xg >= -1.0f) && (xg <= (float)W)) ? 1.0f : 0.0f;
        const float x = fminf(fmaxf(xg, 0.0f), (float)(W - 1));
        const int x0 = (int)floorf(x);
        const float lx = x - (float)x0;
        const float hx = 1.0f - lx;
        const int edge = (x0 == W - 1);
        float4 r;
        r.x = __int_as_float(min(x0, W - 2));
        r.y = edge ? 0.0f   : hx * v;
        r.z = edge ? hx * v : lx * v;
        r.w = 0.0f;
        s_xt[tt] = r;
    } else if (t < 2 * PD + OUTD) {
        const int pw = t - 2 * PD;
        float w[4] = {0.0f, 0.0f, 0.0f, 0.0f};
        int ca[2], cb[2];
        float hxv[2], lxv[2];
#pragma unroll
        for (int j = 0; j < 2; ++j) {
            const float xg = x1 + (float)pw * bw + ((float)j + 0.5f) * bw * 0.5f;
            const float v = ((xg >= -1.0f) && (xg <= (float)W)) ? 1.0f : 0.0f;
            const float x = fminf(fmaxf(xg, 0.0f), (float)(W - 1));
            const int x0 = (int)floorf(x);
            const float lx = x - (float)x0;
            ca[j] = x0;
            cb[j] = min(x0 + 1, W - 1);
            hxv[j] = (1.0f - lx) * v;
            lxv[j] = lx * v;
        }
        const int ok = (cb[1] - ca[0]) <= 3;
        int xf = min(ca[0], W - 4);
        if (xf < 0) xf = 0;
        w[(ca[0] - xf) & 3] += hxv[0];
        w[(cb[0] - xf) & 3] += lxv[0];
        w[(ca[1] - xf) & 3] += hxv[1];
        w[(cb[1] - xf) & 3] += lxv[1];
        float4 wv; wv.x = w[0]; wv.y = w[1]; wv.z = w[2]; wv.w = w[3];
        s_xw[pw] = wv;
        s_xf[pw] = xf;
        s_ok[pw] = ok;
    }
    __syncthreads();

    const bool fused = s_ok[0] && s_ok[1] && s_ok[2] && s_ok[3] &&
                       s_ok[4] && s_ok[5] && s_ok[6];   // block-uniform

    float* __restrict__ outbase = out + ((size_t)roi * NCH + c0) * 49;

    // per-block elements: CHUNK*49 = 1568 = 6*256 + 32
    if (fused) {
        // ==== fast path: 4 dwordx4/elem; sched_barrier-pinned 4-deep pipeline ====
        auto g4 = [&](const float* __restrict__ fp, int ph, int pw, float4* P) {
            const float4 yt0 = s_yt[2 * ph];
            const float4 yt1 = s_yt[2 * ph + 1];
            const int xf = s_xf[pw];
            P[0] = *(const float4*)(fp + __float_as_int(yt0.x) + xf);
            P[1] = *(const float4*)(fp + __float_as_int(yt0.y) + xf);
            P[2] = *(const float4*)(fp + __float_as_int(yt1.x) + xf);
            P[3] = *(const float4*)(fp + __float_as_int(yt1.y) + xf);
        };
        auto r4 = [&](int ph, int pw, const float4* P) -> float {
            const float4 w   = s_xw[pw];
            const float4 yt0 = s_yt[2 * ph];
            const float4 yt1 = s_yt[2 * ph + 1];
            const float d0 = w.x * P[0].x + w.y * P[0].y + w.z * P[0].z + w.w * P[0].w;
            const float d1 = w.x * P[1].x + w.y * P[1].y + w.z * P[1].z + w.w * P[1].w;
            const float d2 = w.x * P[2].x + w.y * P[2].y + w.z * P[2].z + w.w * P[2].w;
            const float d3 = w.x * P[3].x + w.y * P[3].y + w.z * P[3].z + w.w * P[3].w;
            return yt0.z * d0 + yt0.w * d1 + yt1.z * d2 + yt1.w * d3;
        };

        // group 1: iterations 0..3 (depth 4, 16 outstanding dwordx4)
        {
            int eA[4], phA[4], pwA[4];
            const float* fpA[4];
#pragma unroll
            for (int j = 0; j < 4; ++j) {
                const int e = t + j * 256;
                const int c = e / 49, bin = e - c * 49;
                phA[j] = bin / 7;
                pwA[j] = bin - phA[j] * 7;
                eA[j]  = e;
                fpA[j] = base0 + (size_t)c * plane;
            }
            float4 P[4][4];
#pragma unroll
            for (int j = 0; j < 4; ++j)
                g4(fpA[j], phA[j], pwA[j], P[j]);
            __builtin_amdgcn_sched_barrier(0);
#pragma unroll
            for (int j = 0; j < 4; ++j)
                outbase[eA[j]] = r4(phA[j], pwA[j], P[j]) * 0.25f;
        }
        // group 2: iterations 4..5 (depth 2)
        {
            int eA[2], phA[2], pwA[2];
            const float* fpA[2];
#pragma unroll
            for (int j = 0; j < 2; ++j) {
                const int e = t + (4 + j) * 256;
                const int c = e / 49, bin = e - c * 49;
                phA[j] = bin / 7;
                pwA[j] = bin - phA[j] * 7;
                eA[j]  = e;
                fpA[j] = base0 + (size_t)c * plane;
            }
            float4 P[2][4];
#pragma unroll
            for (int j = 0; j < 2; ++j)
                g4(fpA[j], phA[j], pwA[j], P[j]);
            __builtin_amdgcn_sched_barrier(0);
#pragma unroll
            for (int j = 0; j < 2; ++j)
                outbase[eA[j]] = r4(phA[j], pwA[j], P[j]) * 0.25f;
        }
        // tail: 32 elements
        if (t < 32) {
            const int e = 1536 + t;
            const int c = e / 49, bin = e - c * 49;
            const int ph = bin / 7, pw = bin - ph * 7;
            const float* fp = base0 + (size_t)c * plane;
            float4 P[4];
            g4(fp, ph, pw, P);
            outbase[e] = r4(ph, pw, P) * 0.25f;
        }
    } else {
        // ==== legacy path (wide bins): 8 dwordx2/elem; pinned 3-deep pipeline ====
        auto gather = [&](const float* __restrict__ fp, int ph, int pw, float2* P) {
#pragma unroll
            for (int sy = 0; sy < SRD; ++sy) {
                const float4 yt = s_yt[ph * SRD + sy];
                const int ro0 = __float_as_int(yt.x);
                const int ro1 = __float_as_int(yt.y);
#pragma unroll
                for (int sx = 0; sx < SRD; ++sx) {
                    const float4 xt = s_xt[pw * SRD + sx];
                    const int xa = __float_as_int(xt.x);
                    P[(sy * SRD + sx) * 2 + 0] = *(const float2*)(fp + ro0 + xa);
                    P[(sy * SRD + sx) * 2 + 1] = *(const float2*)(fp + ro1 + xa);
                }
            }
        };
        auto reduce = [&](int ph, int pw, const float2* P) -> float {
            float acc = 0.0f;
#pragma unroll
            for (int sy = 0; sy < SRD; ++sy) {
                const float4 yt = s_yt[ph * SRD + sy];
                const float hy = yt.z, ly = yt.w;
#pragma unroll
                for (int sx = 0; sx < SRD; ++sx) {
                    const float4 xt = s_xt[pw * SRD + sx];
                    const float wlo = xt.y, whi = xt.z;
                    const float2 p0 = P[(sy * SRD + sx) * 2 + 0];
                    const float2 p1 = P[(sy * SRD + sx) * 2 + 1];
                    acc += hy * (wlo * p0.x + whi * p0.y)
                         + ly * (wlo * p1.x + whi * p1.y);
                }
            }
            return acc;
        };

        // two groups of depth 3 (iterations 0..2 and 3..5)
#pragma unroll
        for (int kk = 0; kk < 2; ++kk) {
            int eA[3], phA[3], pwA[3];
            const float* fpA[3];
#pragma unroll
            for (int j = 0; j < 3; ++j) {
                const int e = t + (kk * 3 + j) * 256;
                const int c = e / 49, bin = e - c * 49;
                phA[j] = bin / 7;
                pwA[j] = bin - phA[j] * 7;
                eA[j]  = e;
                fpA[j] = base0 + (size_t)c * plane;
            }
            float2 P[3][8];
#pragma unroll
            for (int j = 0; j < 3; ++j)
                gather(fpA[j], phA[j], pwA[j], P[j]);
            __builtin_amdgcn_sched_barrier(0);
#pragma unroll
            for (int j = 0; j < 3; ++j)
                outbase[eA[j]] = reduce(phA[j], pwA[j], P[j]) * 0.25f;
        }
        if (t < 32) {
            const int e = 1536 + t;
            const int c = e / 49, bin = e - c * 49;
            const int ph = bin / 7, pw = bin - ph * 7;
            const float* fp = base0 + (size_t)c * plane;
            float2 P[8];
            gather(fp, ph, pw, P);
            outbase[e] = reduce(ph, pw, P) * 0.25f;
        }
    }
}

extern "C" void kernel_launch(void* const* d_in, const int* in_sizes, int n_in,
                              void* d_out, int out_size, void* d_ws, size_t ws_size,
                              hipStream_t stream) {
    const float* f0    = (const float*)d_in[0];
    const float* f1    = (const float*)d_in[1];
    const float* f2    = (const float*)d_in[2];
    const float* f3    = (const float*)d_in[3];
    const float* boxes = (const float*)d_in[4];
    const int*   ids   = (const int*)d_in[5];
    float* out = (float*)d_out;
    int*   order = (int*)d_ws;

    const int N = in_sizes[4] / 4;   // number of ROIs (1000)

    sort_kernel<<<1, 1024, 0, stream>>>(boxes, ids, order, N);

    dim3 grid(N, NCH / CHUNK);
    pooler_kernel<<<grid, 256, 0, stream>>>(f0, f1, f2, f3, boxes, ids, order, out, N);
}